// Round 1
// baseline (979.121 us; speedup 1.0000x reference)
//
#include <hip/hip_runtime.h>
#include <math.h>

// ---------------------------------------------------------------------------
// Problem geometry: B=16, S=1024, E=320, H=8, DH=40 -> M = B*S = 16384 rows.
// All heavy layers are X[M,K] @ W[N,K]^T + bias (optionally ReLU).
// ---------------------------------------------------------------------------

#define M_ROWS 16384
#define TILE 64
#define BK 16

// Tiled fp32 GEMM: C[M,N] = act(X[M,K] @ W[N,K]^T + bias)
// Dual-input support: for k >= ksplit, read from X2 (concat along K).
// X row stride = ksplit (== K when X2 unused); X2 row stride = K - ksplit.
template<bool RELU>
__global__ __launch_bounds__(256) void gemm_bias_act(
    const float* __restrict__ X, const float* __restrict__ X2, int ksplit,
    const float* __restrict__ W, const float* __restrict__ bias,
    float* __restrict__ C, int M, int N, int K)
{
    __shared__ float Xs[BK][TILE];
    __shared__ float Ws[BK][TILE];

    const int tid = threadIdx.x;
    const int tr  = tid >> 4;    // 0..15 (row group)
    const int tc  = tid & 15;    // 0..15 (col group)
    const int m0  = blockIdx.y * TILE;
    const int n0  = blockIdx.x * TILE;

    const int lrow = tid >> 4;   // 0..15
    const int lcol = tid & 15;   // k within tile

    float acc[4][4] = {};

    for (int k0 = 0; k0 < K; k0 += BK) {
        const int gk = k0 + lcol;
        // X tile: rows m0..m0+63 (M,K divisible by tile sizes -> no M/K guards)
        #pragma unroll
        for (int r = 0; r < TILE; r += 16) {
            int gm = m0 + lrow + r;
            float v;
            if (gk < ksplit) v = X [(size_t)gm * ksplit + gk];
            else             v = X2[(size_t)gm * (K - ksplit) + (gk - ksplit)];
            Xs[lcol][lrow + r] = v;
        }
        // W tile: rows n0..n0+63 over N (guard: N may be 160)
        #pragma unroll
        for (int r = 0; r < TILE; r += 16) {
            int gn = n0 + lrow + r;
            Ws[lcol][lrow + r] = (gn < N) ? W[(size_t)gn * K + gk] : 0.0f;
        }
        __syncthreads();

        #pragma unroll
        for (int kk = 0; kk < BK; ++kk) {
            float4 a = *reinterpret_cast<const float4*>(&Xs[kk][tr * 4]);
            float4 b = *reinterpret_cast<const float4*>(&Ws[kk][tc * 4]);
            float av[4] = {a.x, a.y, a.z, a.w};
            float bv[4] = {b.x, b.y, b.z, b.w};
            #pragma unroll
            for (int i = 0; i < 4; ++i)
                #pragma unroll
                for (int j = 0; j < 4; ++j)
                    acc[i][j] += av[i] * bv[j];
        }
        __syncthreads();
    }

    #pragma unroll
    for (int i = 0; i < 4; ++i) {
        const int gm = m0 + tr * 4 + i;
        #pragma unroll
        for (int j = 0; j < 4; ++j) {
            const int gn = n0 + tc * 4 + j;
            if (gn < N) {
                float v = acc[i][j] + bias[gn];
                if (RELU) v = fmaxf(v, 0.0f);
                C[(size_t)gm * N + gn] = v;
            }
        }
    }
}

// Attention over the batch axis: for each (s,h), 16x16 scores over DH=40.
// Q/K/V/CTX layout: [B=16, S=1024, E=320], elem (l,s,h,d) at l*327680 + s*320 + h*40 + d
__global__ __launch_bounds__(256) void attn_kernel(
    const float* __restrict__ Q, const float* __restrict__ K,
    const float* __restrict__ V, float* __restrict__ CTX)
{
    __shared__ float q_s[16][40];
    __shared__ float k_s[16][40];
    __shared__ float v_s[16][40];
    __shared__ float p_s[16][16];

    const int s   = blockIdx.x >> 3;   // H = 8
    const int h   = blockIdx.x & 7;
    const int tid = threadIdx.x;
    const size_t base = (size_t)s * 320 + (size_t)h * 40;

    for (int idx = tid; idx < 16 * 40; idx += 256) {
        int l = idx / 40, d = idx % 40;
        size_t g = base + (size_t)l * 327680 + d;
        q_s[l][d] = Q[g];
        k_s[l][d] = K[g];
        v_s[l][d] = V[g];
    }
    __syncthreads();

    {
        int l = tid >> 4, m = tid & 15;
        float acc = 0.f;
        #pragma unroll
        for (int d = 0; d < 40; ++d) acc += q_s[l][d] * k_s[m][d];
        p_s[l][m] = acc * 0.15811388300841897f;   // 1/sqrt(40)
    }
    __syncthreads();

    if (tid < 16) {
        const int l = tid;
        float mx = p_s[l][0];
        #pragma unroll
        for (int m = 1; m < 16; ++m) mx = fmaxf(mx, p_s[l][m]);
        float e[16];
        float sum = 0.f;
        #pragma unroll
        for (int m = 0; m < 16; ++m) { e[m] = expf(p_s[l][m] - mx); sum += e[m]; }
        float inv = 1.0f / sum;
        #pragma unroll
        for (int m = 0; m < 16; ++m) p_s[l][m] = e[m] * inv;
    }
    __syncthreads();

    for (int idx = tid; idx < 16 * 40; idx += 256) {
        int l = idx / 40, d = idx % 40;
        float acc = 0.f;
        #pragma unroll
        for (int m = 0; m < 16; ++m) acc += p_s[l][m] * v_s[m][d];
        CTX[base + (size_t)l * 327680 + d] = acc;
    }
}

// One wave per row: out[row, n] = dot(X[row,:K], W[n,:K]) + b[n], n < N (N small: 1 or 3)
__global__ __launch_bounds__(256) void rowdot_small(
    const float* __restrict__ X, const float* __restrict__ W,
    const float* __restrict__ bias, float* __restrict__ out,
    int M, int K, int N)
{
    const int wave = (int)((blockIdx.x * 256 + threadIdx.x) >> 6);
    const int lane = threadIdx.x & 63;
    if (wave >= M) return;
    for (int n = 0; n < N; ++n) {
        float s = 0.f;
        for (int j = lane; j < K; j += 64)
            s += X[(size_t)wave * K + j] * W[(size_t)n * K + j];
        #pragma unroll
        for (int off = 32; off; off >>= 1) s += __shfl_down(s, off);
        if (lane == 0) out[(size_t)wave * N + n] = s + bias[n];
    }
}

// contact_map[b,s,:] = prob[b*S+s] ; 1024 floats per row, 256 threads x float4
__global__ __launch_bounds__(256) void contact_kernel(
    const float* __restrict__ prob, float* __restrict__ out)
{
    const int row = blockIdx.x;
    const float p = prob[row];
    float4 v = make_float4(p, p, p, p);
    reinterpret_cast<float4*>(out + (size_t)row * 1024)[threadIdx.x] = v;
}

extern "C" void kernel_launch(void* const* d_in, const int* in_sizes, int n_in,
                              void* d_out, int out_size, void* d_ws, size_t ws_size,
                              hipStream_t stream)
{
    const float* x    = (const float*)d_in[0];
    const float* fpW1 = (const float*)d_in[1];
    const float* fpb1 = (const float*)d_in[2];
    const float* fpW2 = (const float*)d_in[3];
    const float* fpb2 = (const float*)d_in[4];
    const float* Wq   = (const float*)d_in[5];
    const float* bq   = (const float*)d_in[6];
    const float* Wk   = (const float*)d_in[7];
    const float* bk   = (const float*)d_in[8];
    const float* Wv   = (const float*)d_in[9];
    const float* bv   = (const float*)d_in[10];
    const float* Wo   = (const float*)d_in[11];
    const float* bo   = (const float*)d_in[12];
    const float* mW1  = (const float*)d_in[13];
    const float* mb1  = (const float*)d_in[14];
    const float* mW2  = (const float*)d_in[15];
    const float* mb2  = (const float*)d_in[16];
    const float* pW1  = (const float*)d_in[17];
    const float* pb1  = (const float*)d_in[18];
    const float* pW2  = (const float*)d_in[19];
    const float* pb2  = (const float*)d_in[20];
    const float* pW3  = (const float*)d_in[21];
    const float* pb3  = (const float*)d_in[22];

    float* out      = (float*)d_out;
    float* out_bb   = out;                           // [16384,320]
    float* out_side = out + 5242880;                 // [16384,320]
    float* out_cm   = out + 2 * 5242880;             // [16,1024,1024]
    float* out_ref  = out + 2 * 5242880 + 16777216;  // [16384,3]

    float* ws = (float*)d_ws;
    float* A  = ws;                 // [16384,320] scratch
    float* B1 = ws + 1 * 5242880;   // [16384,320]
    float* B2 = ws + 2 * 5242880;   // [16384,320] (also holds [16384,160])
    float* B3 = ws + 3 * 5242880;   // [16384,320] (also holds [16384,1])

    const int M = M_ROWS;
    dim3 blk(256);
    auto grd = [](int N) { return dim3((N + TILE - 1) / TILE, M_ROWS / TILE); };

    // backbone = fp2( relu( fp1(x) ) )
    gemm_bias_act<true ><<<grd(320), blk, 0, stream>>>(x,      nullptr, 320, fpW1, fpb1, A,       M, 320, 320);
    gemm_bias_act<false><<<grd(320), blk, 0, stream>>>(A,      nullptr, 320, fpW2, fpb2, out_bb,  M, 320, 320);
    // side = fp2( relu( fp1(backbone) ) )
    gemm_bias_act<true ><<<grd(320), blk, 0, stream>>>(out_bb, nullptr, 320, fpW1, fpb1, A,       M, 320, 320);
    gemm_bias_act<false><<<grd(320), blk, 0, stream>>>(A,      nullptr, 320, fpW2, fpb2, out_side,M, 320, 320);

    // q,k,v projections of x
    gemm_bias_act<false><<<grd(320), blk, 0, stream>>>(x, nullptr, 320, Wq, bq, B1, M, 320, 320);
    gemm_bias_act<false><<<grd(320), blk, 0, stream>>>(x, nullptr, 320, Wk, bk, B2, M, 320, 320);
    gemm_bias_act<false><<<grd(320), blk, 0, stream>>>(x, nullptr, 320, Wv, bv, B3, M, 320, 320);

    // attention over batch axis -> ctx in A
    attn_kernel<<<dim3(1024 * 8), blk, 0, stream>>>(B1, B2, B3, A);

    // attn_out = ctx @ Wo^T + bo  -> B1
    gemm_bias_act<false><<<grd(320), blk, 0, stream>>>(A, nullptr, 320, Wo, bo, B1, M, 320, 320);

    // contact MLP: B2 = relu(B1 @ mW1^T + mb1) [16384,160]; B3 = B2 @ mW2^T + mb2 [16384,1]
    gemm_bias_act<true ><<<grd(160), blk, 0, stream>>>(B1, nullptr, 320, mW1, mb1, B2, M, 160, 320);
    rowdot_small<<<dim3(M_ROWS / 4), blk, 0, stream>>>(B2, mW2, mb2, B3, M, 160, 1);
    contact_kernel<<<dim3(M_ROWS), blk, 0, stream>>>(B3, out_cm);

    // position predictor: A = relu(concat(bb,side) @ pW1^T + pb1)  (dual-input GEMM, K=640)
    gemm_bias_act<true ><<<grd(320), blk, 0, stream>>>(out_bb, out_side, 320, pW1, pb1, A, M, 320, 640);
    gemm_bias_act<true ><<<grd(160), blk, 0, stream>>>(A, nullptr, 320, pW2, pb2, B1, M, 160, 320);
    rowdot_small<<<dim3(M_ROWS / 4), blk, 0, stream>>>(B1, pW3, pb3, out_ref, M, 160, 3);
}

// Round 2
// 217.101 us; speedup vs baseline: 4.5100x; 4.5100x over previous
//
#include <hip/hip_runtime.h>
#include <math.h>

// B=16, S=1024, E=320, H=8, DH=40 -> M = 16384 rows everywhere.
// All heavy layers: X[M,K] @ W[N,K]^T + bias (optional ReLU), done in bf16 MFMA.

#define M_ROWS 16384

typedef float f32x4 __attribute__((ext_vector_type(4)));
typedef short short8 __attribute__((ext_vector_type(8)));
typedef __bf16 bf16x8 __attribute__((ext_vector_type(8)));

typedef const __attribute__((address_space(1))) void* gas_ptr;
typedef __attribute__((address_space(3))) void* las_ptr;

__device__ __forceinline__ unsigned short f2bf(float f) {
    union { float f; unsigned int u; } v; v.f = f;
    unsigned int u = v.u + 0x7FFFu + ((v.u >> 16) & 1u);   // RNE
    return (unsigned short)(u >> 16);
}
__device__ __forceinline__ float bf2f(unsigned short s) {
    union { unsigned int u; float f; } v; v.u = ((unsigned int)s) << 16;
    return v.f;
}

// ---------------------------------------------------------------------------
// bf16 MFMA GEMM: C[M,N] = act(X[M,K] @ W[N,K]^T + bias)
// BM=128, BK=64, 4 waves. BN=64 (wave grid 2x2, 64x32/wave) or BN=32 (4x1,
// 32x32/wave). Dual input along K: k >= ksplit reads X2 (concat).
// LDS layout: row-major [rows][64] bf16, 8 units of 16B per row, unit-XOR
// swizzled by (row&7). global_load_lds dest is linear; the SOURCE column is
// pre-swizzled (rule #21: both-sides-or-neither).
// MFMA 16x16x32 fragment maps: A[m=l&15][k=(l>>4)*8+j], B[k=(l>>4)*8+j][n=l&15],
// D row=(l>>4)*4+i, col=l&15  (m89/m91-verified).
// ---------------------------------------------------------------------------
template<int BN, bool RELU>
__global__ __launch_bounds__(256) void gemm_mfma(
    const unsigned short* __restrict__ X1, const unsigned short* __restrict__ X2,
    int ksplit, int K,
    const unsigned short* __restrict__ W, const float* __restrict__ bias,
    float* __restrict__ outF, unsigned short* __restrict__ outB, int N)
{
    constexpr int BM = 128, BK = 64;
    constexpr int WROWS = (BN == 64) ? 2 : 4;
    constexpr int WCOLS = 4 / WROWS;
    constexpr int WM = BM / WROWS;   // 64 or 32
    constexpr int WN = BN / WCOLS;   // 32
    constexpr int MF = WM / 16;      // 4 or 2
    constexpr int NF = WN / 16;      // 2

    __shared__ unsigned short As[BM * BK];
    __shared__ unsigned short Bs[BN * BK];

    const int tid  = threadIdx.x;
    const int wave = tid >> 6;
    const int lane = tid & 63;
    const int m0 = blockIdx.y * BM;
    const int n0 = blockIdx.x * BN;
    const int wr = wave / WCOLS;
    const int wc = wave % WCOLS;

    const int sr = lane >> 3;   // row within 8-row staging chunk
    const int su = lane & 7;    // 16B unit within row

    f32x4 acc[MF][NF];
    #pragma unroll
    for (int i = 0; i < MF; ++i)
        #pragma unroll
        for (int j = 0; j < NF; ++j) acc[i][j] = (f32x4)0.f;

    for (int k0 = 0; k0 < K; k0 += BK) {
        // ---- stage A tile (BM x 64 bf16 = 16 KB = 16 chunks of 1KB) ----
        #pragma unroll
        for (int i = 0; i < (BM * BK * 2) / 4096; ++i) {
            const int c = i * 4 + wave;
            const int r = c * 8 + sr;
            const int gk = k0 + (su ^ (r & 7)) * 8;   // pre-swizzled source col
            const unsigned short* src;
            if (gk < ksplit) src = X1 + (size_t)(m0 + r) * ksplit + gk;
            else             src = X2 + (size_t)(m0 + r) * (K - ksplit) + (gk - ksplit);
            __builtin_amdgcn_global_load_lds((gas_ptr)src, (las_ptr)&As[c * 512], 16, 0, 0);
        }
        // ---- stage B tile (BN x 64 bf16) ----
        #pragma unroll
        for (int i = 0; i < (BN * BK * 2) / 4096; ++i) {
            const int c = i * 4 + wave;
            const int r = c * 8 + sr;
            const int gk = k0 + (su ^ (r & 7)) * 8;
            const unsigned short* src = W + (size_t)(n0 + r) * K + gk;
            __builtin_amdgcn_global_load_lds((gas_ptr)src, (las_ptr)&Bs[c * 512], 16, 0, 0);
        }
        __syncthreads();   // drains vmcnt before LDS reads

        #pragma unroll
        for (int s = 0; s < 2; ++s) {   // two k=32 sub-steps
            bf16x8 a[MF], b[NF];
            #pragma unroll
            for (int mf = 0; mf < MF; ++mf) {
                const int r  = wr * WM + mf * 16 + (lane & 15);
                const int lu = (s * 4 + (lane >> 4)) ^ (r & 7);
                a[mf] = *reinterpret_cast<const bf16x8*>(&As[r * 64 + lu * 8]);
            }
            #pragma unroll
            for (int nf = 0; nf < NF; ++nf) {
                const int r  = wc * WN + nf * 16 + (lane & 15);
                const int lu = (s * 4 + (lane >> 4)) ^ (r & 7);
                b[nf] = *reinterpret_cast<const bf16x8*>(&Bs[r * 64 + lu * 8]);
            }
            #pragma unroll
            for (int mf = 0; mf < MF; ++mf)
                #pragma unroll
                for (int nf = 0; nf < NF; ++nf)
                    acc[mf][nf] = __builtin_amdgcn_mfma_f32_16x16x32_bf16(
                        a[mf], b[nf], acc[mf][nf], 0, 0, 0);
        }
        __syncthreads();
    }

    #pragma unroll
    for (int nf = 0; nf < NF; ++nf) {
        const int gn = n0 + wc * WN + nf * 16 + (lane & 15);
        const float bv = bias[gn];
        #pragma unroll
        for (int mf = 0; mf < MF; ++mf) {
            #pragma unroll
            for (int i = 0; i < 4; ++i) {
                const int gm = m0 + wr * WM + mf * 16 + (lane >> 4) * 4 + i;
                float v = acc[mf][nf][i] + bv;
                if (RELU) v = fmaxf(v, 0.f);
                if (outF) outF[(size_t)gm * N + gn] = v;
                if (outB) outB[(size_t)gm * N + gn] = f2bf(v);
            }
        }
    }
}

// ---------------------------------------------------------------------------
// Attention over the batch axis: per (s,h), 16x16 scores over DH=40. bf16 I/O.
// elem (l,s,h,d) at l*327680 + s*320 + h*40 + d
// ---------------------------------------------------------------------------
__global__ __launch_bounds__(256) void attn_kernel(
    const unsigned short* __restrict__ Q, const unsigned short* __restrict__ K,
    const unsigned short* __restrict__ V, unsigned short* __restrict__ CTX)
{
    __shared__ float q_s[16][40];
    __shared__ float k_s[16][40];
    __shared__ float v_s[16][40];
    __shared__ float p_s[16][16];

    const int s   = blockIdx.x >> 3;
    const int h   = blockIdx.x & 7;
    const int tid = threadIdx.x;
    const size_t base = (size_t)s * 320 + (size_t)h * 40;

    for (int idx = tid; idx < 16 * 40; idx += 256) {
        int l = idx / 40, d = idx % 40;
        size_t g = base + (size_t)l * 327680 + d;
        q_s[l][d] = bf2f(Q[g]);
        k_s[l][d] = bf2f(K[g]);
        v_s[l][d] = bf2f(V[g]);
    }
    __syncthreads();

    {
        int l = tid >> 4, m = tid & 15;
        float acc = 0.f;
        #pragma unroll
        for (int d = 0; d < 40; ++d) acc += q_s[l][d] * k_s[m][d];
        p_s[l][m] = acc * 0.15811388300841897f;   // 1/sqrt(40)
    }
    __syncthreads();

    if (tid < 16) {
        const int l = tid;
        float mx = p_s[l][0];
        #pragma unroll
        for (int m = 1; m < 16; ++m) mx = fmaxf(mx, p_s[l][m]);
        float e[16]; float sum = 0.f;
        #pragma unroll
        for (int m = 0; m < 16; ++m) { e[m] = expf(p_s[l][m] - mx); sum += e[m]; }
        float inv = 1.0f / sum;
        #pragma unroll
        for (int m = 0; m < 16; ++m) p_s[l][m] = e[m] * inv;
    }
    __syncthreads();

    for (int idx = tid; idx < 16 * 40; idx += 256) {
        int l = idx / 40, d = idx % 40;
        float acc = 0.f;
        #pragma unroll
        for (int m = 0; m < 16; ++m) acc += p_s[l][m] * v_s[m][d];
        CTX[base + (size_t)l * 327680 + d] = f2bf(acc);
    }
}

// One wave per row; X bf16, W/bias fp32 (N is 1 or 3, K=160)
__global__ __launch_bounds__(256) void rowdot_small(
    const unsigned short* __restrict__ X, const float* __restrict__ W,
    const float* __restrict__ bias, float* __restrict__ out,
    int M, int K, int N)
{
    const int wave = (int)((blockIdx.x * 256 + threadIdx.x) >> 6);
    const int lane = threadIdx.x & 63;
    if (wave >= M) return;
    for (int n = 0; n < N; ++n) {
        float s = 0.f;
        for (int j = lane; j < K; j += 64)
            s += bf2f(X[(size_t)wave * K + j]) * W[(size_t)n * K + j];
        #pragma unroll
        for (int off = 32; off; off >>= 1) s += __shfl_down(s, off);
        if (lane == 0) out[(size_t)wave * N + n] = s + bias[n];
    }
}

__global__ __launch_bounds__(256) void contact_kernel(
    const float* __restrict__ prob, float* __restrict__ out)
{
    const int row = blockIdx.x;
    const float p = prob[row];
    reinterpret_cast<float4*>(out + (size_t)row * 1024)[threadIdx.x] =
        make_float4(p, p, p, p);
}

// fp32 -> bf16 converters
__global__ __launch_bounds__(256) void conv_f2b(
    const float* __restrict__ src, unsigned short* __restrict__ dst, int n)
{
    int idx = (blockIdx.x * 256 + threadIdx.x) * 4;
    if (idx >= n) return;
    float4 v = *reinterpret_cast<const float4*>(&src[idx]);
    unsigned int lo = (unsigned int)f2bf(v.x) | ((unsigned int)f2bf(v.y) << 16);
    unsigned int hi = (unsigned int)f2bf(v.z) | ((unsigned int)f2bf(v.w) << 16);
    uint2 packed = make_uint2(lo, hi);
    *reinterpret_cast<uint2*>(&dst[idx]) = packed;
}

struct ConvDesc { const float* src; unsigned short* dst; int n; };
struct ConvPack { ConvDesc d[9]; };
__global__ __launch_bounds__(256) void conv_many(ConvPack p)
{
    ConvDesc cd = p.d[blockIdx.y];
    int idx = (blockIdx.x * 256 + threadIdx.x) * 4;
    if (idx >= cd.n) return;
    float4 v = *reinterpret_cast<const float4*>(&cd.src[idx]);
    unsigned int lo = (unsigned int)f2bf(v.x) | ((unsigned int)f2bf(v.y) << 16);
    unsigned int hi = (unsigned int)f2bf(v.z) | ((unsigned int)f2bf(v.w) << 16);
    *reinterpret_cast<uint2*>(&cd.dst[idx]) = make_uint2(lo, hi);
}

extern "C" void kernel_launch(void* const* d_in, const int* in_sizes, int n_in,
                              void* d_out, int out_size, void* d_ws, size_t ws_size,
                              hipStream_t stream)
{
    const float* x    = (const float*)d_in[0];
    const float* fpW1 = (const float*)d_in[1];
    const float* fpb1 = (const float*)d_in[2];
    const float* fpW2 = (const float*)d_in[3];
    const float* fpb2 = (const float*)d_in[4];
    const float* Wq   = (const float*)d_in[5];
    const float* bq   = (const float*)d_in[6];
    const float* Wk   = (const float*)d_in[7];
    const float* bk   = (const float*)d_in[8];
    const float* Wv   = (const float*)d_in[9];
    const float* bv   = (const float*)d_in[10];
    const float* Wo   = (const float*)d_in[11];
    const float* bo   = (const float*)d_in[12];
    const float* mW1  = (const float*)d_in[13];
    const float* mb1  = (const float*)d_in[14];
    const float* mW2  = (const float*)d_in[15];
    const float* mb2  = (const float*)d_in[16];
    const float* pW1  = (const float*)d_in[17];
    const float* pb1  = (const float*)d_in[18];
    const float* pW2  = (const float*)d_in[19];
    const float* pb2  = (const float*)d_in[20];
    const float* pW3  = (const float*)d_in[21];
    const float* pb3  = (const float*)d_in[22];

    float* out      = (float*)d_out;
    float* out_bb   = out;
    float* out_side = out + 5242880;
    float* out_cm   = out + 2 * 5242880;
    float* out_ref  = out + 2 * 5242880 + 16777216;

    unsigned short* ws = (unsigned short*)d_ws;
    const size_t BUF = 5242880;              // one [16384,320] bf16 buffer
    unsigned short* xb    = ws;
    unsigned short* t1b   = ws + 1 * BUF;
    unsigned short* bbB   = ws + 2 * BUF;
    unsigned short* sideB = ws + 3 * BUF;
    unsigned short* qb    = ws + 4 * BUF;
    unsigned short* kb    = ws + 5 * BUF;
    unsigned short* vb    = ws + 6 * BUF;
    unsigned short* wb    = ws + 7 * BUF;    // bf16 weights region
    unsigned short* fpW1b = wb;              // 102400
    unsigned short* fpW2b = wb + 102400;
    unsigned short* Wqb   = wb + 204800;
    unsigned short* Wkb   = wb + 307200;
    unsigned short* Wvb   = wb + 409600;
    unsigned short* Wob   = wb + 512000;
    unsigned short* mW1b  = wb + 614400;     // 51200
    unsigned short* pW1b  = wb + 665600;     // 204800
    unsigned short* pW2b  = wb + 870400;     // 51200
    float* probF = (float*)(ws + 7 * BUF + 1048576);   // 16384 fp32

    const int M = M_ROWS;
    dim3 blk(256);
    const dim3 g320(5, M / 128);    // BN=64, N=320
    const dim3 g160(5, M / 128);    // BN=32, N=160

    // --- fp32 -> bf16 conversions ---
    conv_f2b<<<dim3(5242880 / 1024), blk, 0, stream>>>(x, xb, 5242880);
    ConvPack cp;
    cp.d[0] = {fpW1, fpW1b, 102400}; cp.d[1] = {fpW2, fpW2b, 102400};
    cp.d[2] = {Wq, Wqb, 102400};     cp.d[3] = {Wk, Wkb, 102400};
    cp.d[4] = {Wv, Wvb, 102400};     cp.d[5] = {Wo, Wob, 102400};
    cp.d[6] = {mW1, mW1b, 51200};    cp.d[7] = {pW1, pW1b, 204800};
    cp.d[8] = {pW2, pW2b, 51200};
    conv_many<<<dim3(200, 9), blk, 0, stream>>>(cp);

    // --- backbone / side ---
    gemm_mfma<64, true ><<<g320, blk, 0, stream>>>(xb,  xb, 320, 320, fpW1b, fpb1, nullptr, t1b, 320);
    gemm_mfma<64, false><<<g320, blk, 0, stream>>>(t1b, t1b, 320, 320, fpW2b, fpb2, out_bb, bbB, 320);
    gemm_mfma<64, true ><<<g320, blk, 0, stream>>>(bbB, bbB, 320, 320, fpW1b, fpb1, nullptr, t1b, 320);
    gemm_mfma<64, false><<<g320, blk, 0, stream>>>(t1b, t1b, 320, 320, fpW2b, fpb2, out_side, sideB, 320);

    // --- q,k,v projections ---
    gemm_mfma<64, false><<<g320, blk, 0, stream>>>(xb, xb, 320, 320, Wqb, bq, nullptr, qb, 320);
    gemm_mfma<64, false><<<g320, blk, 0, stream>>>(xb, xb, 320, 320, Wkb, bk, nullptr, kb, 320);
    gemm_mfma<64, false><<<g320, blk, 0, stream>>>(xb, xb, 320, 320, Wvb, bv, nullptr, vb, 320);

    // --- attention over batch axis -> ctx (t1b) ---
    attn_kernel<<<dim3(1024 * 8), blk, 0, stream>>>(qb, kb, vb, t1b);

    // --- attn_out = ctx @ Wo^T + bo -> qb ---
    gemm_mfma<64, false><<<g320, blk, 0, stream>>>(t1b, t1b, 320, 320, Wob, bo, nullptr, qb, 320);

    // --- contact MLP ---
    gemm_mfma<32, true ><<<g160, blk, 0, stream>>>(qb, qb, 320, 320, mW1b, mb1, nullptr, kb, 160);
    rowdot_small<<<dim3(M / 4), blk, 0, stream>>>(kb, mW2, mb2, probF, M, 160, 1);
    contact_kernel<<<dim3(M), blk, 0, stream>>>(probF, out_cm);

    // --- position predictor (dual-input K=640) ---
    gemm_mfma<64, true ><<<g320, blk, 0, stream>>>(bbB, sideB, 320, 640, pW1b, pb1, nullptr, t1b, 320);
    gemm_mfma<32, true ><<<g160, blk, 0, stream>>>(t1b, t1b, 320, 320, pW2b, pb2, nullptr, kb, 160);
    rowdot_small<<<dim3(M / 4), blk, 0, stream>>>(kb, pW3, pb3, out_ref, M, 160, 3);
}

// Round 3
// 169.100 us; speedup vs baseline: 5.7902x; 1.2839x over previous
//
#include <hip/hip_runtime.h>
#include <math.h>

// B=16, S=1024, E=320, H=8, DH=40 -> M = 16384 rows.
// All heavy layers bf16 MFMA. 8 launches total via block-range megakernels.

#define M_ROWS 16384

typedef float f32x4 __attribute__((ext_vector_type(4)));
typedef __bf16 bf16x8 __attribute__((ext_vector_type(8)));
typedef unsigned short ushort_t;

typedef const __attribute__((address_space(1))) void* gas_ptr;
typedef __attribute__((address_space(3))) void* las_ptr;

__device__ __forceinline__ unsigned short f2bf(float f) {
    union { float f; unsigned int u; } v; v.f = f;
    unsigned int u = v.u + 0x7FFFu + ((v.u >> 16) & 1u);   // RNE
    return (unsigned short)(u >> 16);
}
__device__ __forceinline__ float bf2f(unsigned short s) {
    union { unsigned int u; float f; } v; v.u = ((unsigned int)s) << 16;
    return v.f;
}

// ---------------------------------------------------------------------------
// GEMM core (verified round 2): BM=128, BK=64, 4 waves, mfma 16x16x32 bf16.
// BN=64 -> wave grid 2x2 (64x32/wave, MF=4); BN=32 -> 4x1 (32x32/wave, MF=2).
// LDS row-major [rows][64] bf16, unit-XOR swizzle by (row&7); global_load_lds
// dest linear, SOURCE column pre-swizzled (both-sides rule #21).
// ---------------------------------------------------------------------------
template<int BN>
__device__ __forceinline__ void gemm_core(
    int tx, int ty,
    const ushort_t* __restrict__ X1, const ushort_t* __restrict__ X2,
    int ksplit, int K, const ushort_t* __restrict__ W,
    char* smem, f32x4 (*acc)[2])
{
    constexpr int BM = 128, BK = 64;
    constexpr int WROWS = (BN == 64) ? 2 : 4;
    constexpr int WCOLS = 4 / WROWS;
    constexpr int WM = BM / WROWS;
    constexpr int WN = BN / WCOLS;   // 32
    constexpr int MF = WM / 16;
    constexpr int NF = WN / 16;      // 2

    ushort_t* As = (ushort_t*)smem;
    ushort_t* Bs = As + BM * BK;

    const int tid  = threadIdx.x;
    const int wave = tid >> 6;
    const int lane = tid & 63;
    const int m0 = ty * BM;
    const int n0 = tx * BN;
    const int wr = wave / WCOLS;
    const int wc = wave % WCOLS;
    const int sr = lane >> 3;
    const int su = lane & 7;

    for (int k0 = 0; k0 < K; k0 += BK) {
        #pragma unroll
        for (int i = 0; i < (BM * BK * 2) / 4096; ++i) {
            const int c = i * 4 + wave;
            const int r = c * 8 + sr;
            const int gk = k0 + (su ^ (r & 7)) * 8;
            const ushort_t* src;
            if (gk < ksplit) src = X1 + (size_t)(m0 + r) * ksplit + gk;
            else             src = X2 + (size_t)(m0 + r) * (K - ksplit) + (gk - ksplit);
            __builtin_amdgcn_global_load_lds((gas_ptr)src, (las_ptr)&As[c * 512], 16, 0, 0);
        }
        #pragma unroll
        for (int i = 0; i < (BN * BK * 2) / 4096; ++i) {
            const int c = i * 4 + wave;
            const int r = c * 8 + sr;
            const int gk = k0 + (su ^ (r & 7)) * 8;
            const ushort_t* src = W + (size_t)(n0 + r) * K + gk;
            __builtin_amdgcn_global_load_lds((gas_ptr)src, (las_ptr)&Bs[c * 512], 16, 0, 0);
        }
        __syncthreads();

        #pragma unroll
        for (int s = 0; s < 2; ++s) {
            bf16x8 a[MF], b[NF];
            #pragma unroll
            for (int mf = 0; mf < MF; ++mf) {
                const int r  = wr * WM + mf * 16 + (lane & 15);
                const int lu = (s * 4 + (lane >> 4)) ^ (r & 7);
                a[mf] = *reinterpret_cast<const bf16x8*>(&As[r * 64 + lu * 8]);
            }
            #pragma unroll
            for (int nf = 0; nf < NF; ++nf) {
                const int r  = wc * WN + nf * 16 + (lane & 15);
                const int lu = (s * 4 + (lane >> 4)) ^ (r & 7);
                b[nf] = *reinterpret_cast<const bf16x8*>(&Bs[r * 64 + lu * 8]);
            }
            #pragma unroll
            for (int mf = 0; mf < MF; ++mf)
                #pragma unroll
                for (int nf = 0; nf < NF; ++nf)
                    acc[mf][nf] = __builtin_amdgcn_mfma_f32_16x16x32_bf16(
                        a[mf], b[nf], acc[mf][nf], 0, 0, 0);
        }
        __syncthreads();
    }
}

template<int BN, bool RELU>
__device__ __forceinline__ void gemm_store(
    int tx, int ty, f32x4 (*acc)[2], const float* __restrict__ bias,
    float* __restrict__ outF, ushort_t* __restrict__ outB, int N)
{
    constexpr int WROWS = (BN == 64) ? 2 : 4;
    constexpr int WCOLS = 4 / WROWS;
    constexpr int WM = 128 / WROWS;
    constexpr int WN = BN / WCOLS;
    constexpr int MF = WM / 16;

    const int tid  = threadIdx.x;
    const int wave = tid >> 6;
    const int lane = tid & 63;
    const int wr = wave / WCOLS;
    const int wc = wave % WCOLS;

    #pragma unroll
    for (int nf = 0; nf < 2; ++nf) {
        const int gn = tx * BN + wc * WN + nf * 16 + (lane & 15);
        const float bv = bias[gn];
        #pragma unroll
        for (int mf = 0; mf < MF; ++mf) {
            #pragma unroll
            for (int i = 0; i < 4; ++i) {
                const int gm = ty * 128 + wr * WM + mf * 16 + (lane >> 4) * 4 + i;
                float v = acc[mf][nf][i] + bv;
                if (RELU) v = fmaxf(v, 0.f);
                if (outF) outF[(size_t)gm * N + gn] = v;
                if (outB) outB[(size_t)gm * N + gn] = f2bf(v);
            }
        }
    }
}

template<int BN, bool RELU>
__device__ __forceinline__ void gemm_full(
    int bid, int ntx,
    const ushort_t* X1, const ushort_t* X2, int ksplit, int K,
    const ushort_t* W, const float* bias,
    float* outF, ushort_t* outB, int N, char* smem)
{
    const int tx = bid % ntx, ty = bid / ntx;
    constexpr int MF = (BN == 64) ? 4 : 2;
    f32x4 acc[MF][2];
    #pragma unroll
    for (int i = 0; i < MF; ++i) { acc[i][0] = (f32x4)0.f; acc[i][1] = (f32x4)0.f; }
    gemm_core<BN>(tx, ty, X1, X2, ksplit, K, W, smem, acc);
    gemm_store<BN, RELU>(tx, ty, acc, bias, outF, outB, N);
}

// --- attention over batch axis (per (s,h): 16x16 scores over DH=40) ---------
__device__ __forceinline__ void attn_dev(
    int ab, const ushort_t* __restrict__ qkv, ushort_t* __restrict__ ctx, char* smem)
{
    float* q_s = (float*)smem;            // [16][40]
    float* k_s = q_s + 16 * 40;
    float* v_s = k_s + 16 * 40;
    float* p_s = v_s + 16 * 40;           // [16][16]

    const int s   = ab >> 3;
    const int h   = ab & 7;
    const int tid = threadIdx.x;
    const int hb  = h * 40;

    for (int idx = tid; idx < 16 * 40; idx += 256) {
        int l = idx / 40, d = idx % 40;
        size_t row = (size_t)(l * 1024 + s) * 960;
        q_s[idx] = bf2f(qkv[row + hb + d]);
        k_s[idx] = bf2f(qkv[row + 320 + hb + d]);
        v_s[idx] = bf2f(qkv[row + 640 + hb + d]);
    }
    __syncthreads();

    {
        int l = tid >> 4, m = tid & 15;
        float acc = 0.f;
        #pragma unroll
        for (int d = 0; d < 40; ++d) acc += q_s[l * 40 + d] * k_s[m * 40 + d];
        p_s[l * 16 + m] = acc * 0.15811388300841897f;   // 1/sqrt(40)
    }
    __syncthreads();

    if (tid < 16) {
        const int l = tid;
        float mx = p_s[l * 16];
        #pragma unroll
        for (int m = 1; m < 16; ++m) mx = fmaxf(mx, p_s[l * 16 + m]);
        float e[16]; float sum = 0.f;
        #pragma unroll
        for (int m = 0; m < 16; ++m) { e[m] = expf(p_s[l * 16 + m] - mx); sum += e[m]; }
        float inv = 1.0f / sum;
        #pragma unroll
        for (int m = 0; m < 16; ++m) p_s[l * 16 + m] = e[m] * inv;
    }
    __syncthreads();

    for (int idx = tid; idx < 16 * 40; idx += 256) {
        int l = idx / 40, d = idx % 40;
        float acc = 0.f;
        #pragma unroll
        for (int m = 0; m < 16; ++m) acc += p_s[l * 16 + m] * v_s[m * 40 + d];
        ctx[(size_t)(l * 1024 + s) * 320 + hb + d] = f2bf(acc);
    }
}

// --- one wave per row, tiny N (1 or 3), K=160 -------------------------------
__device__ __forceinline__ void rowdot_dev(
    int row, const ushort_t* __restrict__ X, int K,
    const float* __restrict__ W, const float* __restrict__ bias,
    float* __restrict__ out, int N)
{
    const int lane = threadIdx.x & 63;
    for (int n = 0; n < N; ++n) {
        float s = 0.f;
        for (int j = lane; j < K; j += 64)
            s += bf2f(X[(size_t)row * K + j]) * W[(size_t)n * K + j];
        #pragma unroll
        for (int off = 32; off; off >>= 1) s += __shfl_down(s, off);
        if (lane == 0) out[(size_t)row * N + n] = s + bias[n];
    }
}

// ================================ kernels ===================================

struct ConvDesc { const float* src; ushort_t* dst; };
struct ConvPack { ConvDesc d[10]; int start[11]; };

__global__ __launch_bounds__(256) void conv_all(ConvPack p)
{
    const int bid = blockIdx.x;
    int i = 0;
    #pragma unroll
    for (int t = 0; t < 10; ++t) if (bid >= p.start[t + 1]) i = t + 1;
    const int local = bid - p.start[i];
    const int idx = (local * 256 + (int)threadIdx.x) * 4;
    float4 v = *reinterpret_cast<const float4*>(&p.d[i].src[idx]);
    unsigned int lo = (unsigned int)f2bf(v.x) | ((unsigned int)f2bf(v.y) << 16);
    unsigned int hi = (unsigned int)f2bf(v.z) | ((unsigned int)f2bf(v.w) << 16);
    *reinterpret_cast<uint2*>(&p.d[i].dst[idx]) = make_uint2(lo, hi);
}

// G1: x -> [fp1(relu) | q | k | v], N=1280
__global__ __launch_bounds__(256) void k_g1(
    const ushort_t* __restrict__ xb, const ushort_t* __restrict__ Wcat,
    const float* __restrict__ fpb1, const float* __restrict__ bq,
    const float* __restrict__ bk, const float* __restrict__ bvv,
    ushort_t* __restrict__ t1b, ushort_t* __restrict__ qkvb)
{
    __shared__ __align__(16) char smem[24 * 1024];
    const int bid = blockIdx.x;
    const int tx = bid % 20, ty = bid / 20;
    f32x4 acc[4][2];
    #pragma unroll
    for (int i = 0; i < 4; ++i) { acc[i][0] = (f32x4)0.f; acc[i][1] = (f32x4)0.f; }
    gemm_core<64>(tx, ty, xb, xb, 320, 320, Wcat, smem, acc);

    const int tid = threadIdx.x, wave = tid >> 6, lane = tid & 63;
    const int wr = wave >> 1, wc = wave & 1;
    #pragma unroll
    for (int nf = 0; nf < 2; ++nf) {
        const int gn = tx * 64 + wc * 32 + nf * 16 + (lane & 15);
        float bv;
        if      (gn < 320) bv = fpb1[gn];
        else if (gn < 640) bv = bq[gn - 320];
        else if (gn < 960) bv = bk[gn - 640];
        else               bv = bvv[gn - 960];
        #pragma unroll
        for (int mf = 0; mf < 4; ++mf) {
            #pragma unroll
            for (int i = 0; i < 4; ++i) {
                const int gm = ty * 128 + wr * 64 + mf * 16 + (lane >> 4) * 4 + i;
                float v = acc[mf][nf][i] + bv;
                if (gn < 320) t1b [(size_t)gm * 320 + gn] = f2bf(fmaxf(v, 0.f));
                else          qkvb[(size_t)gm * 960 + gn - 320] = f2bf(v);
            }
        }
    }
}

// S3: blocks [0,640) G2 (t1b -> fp2 -> bb), [640,8832) attention (qkv -> ctx in xb)
__global__ __launch_bounds__(256) void k_g2_attn(
    const ushort_t* __restrict__ t1b, const ushort_t* __restrict__ fpW2b,
    const float* __restrict__ fpb2, float* __restrict__ out_bb,
    ushort_t* __restrict__ bbB,
    const ushort_t* __restrict__ qkvb, ushort_t* __restrict__ ctxb)
{
    __shared__ __align__(16) char smem[24 * 1024];
    const int bid = blockIdx.x;
    if (bid < 640) gemm_full<64, false>(bid, 5, t1b, t1b, 320, 320, fpW2b, fpb2, out_bb, bbB, 320, smem);
    else           attn_dev(bid - 640, qkvb, ctxb, smem);
}

// S4: blocks [0,640) G3 (ctx -> Wo -> attn_out), [640,1280) G4 (bb -> fp1 relu -> t2)
__global__ __launch_bounds__(256) void k_g3_g4(
    const ushort_t* __restrict__ ctxb, const ushort_t* __restrict__ Wob,
    const float* __restrict__ bo, ushort_t* __restrict__ aoB,
    const ushort_t* __restrict__ bbB, const ushort_t* __restrict__ fpW1b,
    const float* __restrict__ fpb1, ushort_t* __restrict__ t2b)
{
    __shared__ __align__(16) char smem[24 * 1024];
    const int bid = blockIdx.x;
    if (bid < 640) gemm_full<64, false>(bid, 5, ctxb, ctxb, 320, 320, Wob, bo, nullptr, aoB, 320, smem);
    else           gemm_full<64, true >(bid - 640, 5, bbB, bbB, 320, 320, fpW1b, fpb1, nullptr, t2b, 320, smem);
}

// S5: blocks [0,640) G5 (t2 -> fp2 -> side), [640,1280) G6 (attn_out -> mW1 relu, N=160)
__global__ __launch_bounds__(256) void k_g5_g6(
    const ushort_t* __restrict__ t2b, const ushort_t* __restrict__ fpW2b,
    const float* __restrict__ fpb2, float* __restrict__ out_side,
    ushort_t* __restrict__ sideB,
    const ushort_t* __restrict__ aoB, const ushort_t* __restrict__ mW1b,
    const float* __restrict__ mb1, ushort_t* __restrict__ c1)
{
    __shared__ __align__(16) char smem[24 * 1024];
    const int bid = blockIdx.x;
    if (bid < 640) gemm_full<64, false>(bid, 5, t2b, t2b, 320, 320, fpW2b, fpb2, out_side, sideB, 320, smem);
    else           gemm_full<32, true >(bid - 640, 5, aoB, aoB, 320, 320, mW1b, mb1, nullptr, c1, 160, smem);
}

// S6: blocks [0,640) G7 ([bb|side] -> pW1 relu, K=640), [640,4736) rowdot c1 -> prob
__global__ __launch_bounds__(256) void k_g7_rd(
    const ushort_t* __restrict__ bbB, const ushort_t* __restrict__ sideB,
    const ushort_t* __restrict__ pW1b, const float* __restrict__ pb1,
    ushort_t* __restrict__ t3,
    const ushort_t* __restrict__ c1, const float* __restrict__ mW2,
    const float* __restrict__ mb2, float* __restrict__ probF)
{
    __shared__ __align__(16) char smem[24 * 1024];
    const int bid = blockIdx.x;
    if (bid < 640) gemm_full<64, true>(bid, 5, bbB, sideB, 320, 640, pW1b, pb1, nullptr, t3, 320, smem);
    else           rowdot_dev((bid - 640) * 4 + ((int)threadIdx.x >> 6), c1, 160, mW2, mb2, probF, 1);
}

// S7: blocks [0,640) G8 (t3 -> pW2 relu, N=160), [640,17024) contact broadcast
__global__ __launch_bounds__(256) void k_g8_ct(
    const ushort_t* __restrict__ t3, const ushort_t* __restrict__ pW2b,
    const float* __restrict__ pb2, ushort_t* __restrict__ c2,
    const float* __restrict__ probF, float* __restrict__ out_cm)
{
    __shared__ __align__(16) char smem[24 * 1024];
    const int bid = blockIdx.x;
    if (bid < 640) {
        gemm_full<32, true>(bid, 5, t3, t3, 320, 320, pW2b, pb2, nullptr, c2, 160, smem);
    } else {
        const int row = bid - 640;
        const float p = probF[row];
        reinterpret_cast<float4*>(out_cm + (size_t)row * 1024)[threadIdx.x] =
            make_float4(p, p, p, p);
    }
}

// S8: rowdot c2 -> refined [M,3]
__global__ __launch_bounds__(256) void k_rd3(
    const ushort_t* __restrict__ c2, const float* __restrict__ pW3,
    const float* __restrict__ pb3, float* __restrict__ out_ref)
{
    rowdot_dev(blockIdx.x * 4 + ((int)threadIdx.x >> 6), c2, 160, pW3, pb3, out_ref, 3);
}

extern "C" void kernel_launch(void* const* d_in, const int* in_sizes, int n_in,
                              void* d_out, int out_size, void* d_ws, size_t ws_size,
                              hipStream_t stream)
{
    const float* x    = (const float*)d_in[0];
    const float* fpW1 = (const float*)d_in[1];
    const float* fpb1 = (const float*)d_in[2];
    const float* fpW2 = (const float*)d_in[3];
    const float* fpb2 = (const float*)d_in[4];
    const float* Wq   = (const float*)d_in[5];
    const float* bq   = (const float*)d_in[6];
    const float* Wk   = (const float*)d_in[7];
    const float* bk   = (const float*)d_in[8];
    const float* Wv   = (const float*)d_in[9];
    const float* bv   = (const float*)d_in[10];
    const float* Wo   = (const float*)d_in[11];
    const float* bo   = (const float*)d_in[12];
    const float* mW1  = (const float*)d_in[13];
    const float* mb1  = (const float*)d_in[14];
    const float* mW2  = (const float*)d_in[15];
    const float* mb2  = (const float*)d_in[16];
    const float* pW1  = (const float*)d_in[17];
    const float* pb1  = (const float*)d_in[18];
    const float* pW2  = (const float*)d_in[19];
    const float* pb2  = (const float*)d_in[20];
    const float* pW3  = (const float*)d_in[21];
    const float* pb3  = (const float*)d_in[22];

    float* out      = (float*)d_out;
    float* out_bb   = out;
    float* out_side = out + 5242880;
    float* out_cm   = out + 2 * 5242880;
    float* out_ref  = out + 2 * 5242880 + 16777216;

    ushort_t* ws = (ushort_t*)d_ws;
    const size_t BUF = 5242880;
    ushort_t* xb    = ws;              // x bf16; later: ctx; later: c2 [M,160]
    ushort_t* t1b   = ws + 1 * BUF;    // fp1(x) relu; later: t3 (pW1 out)
    ushort_t* bbB   = ws + 2 * BUF;
    ushort_t* sideB = ws + 3 * BUF;
    ushort_t* qkvb  = ws + 4 * BUF;    // [M,960]; later: aoB | t2b | c1
    ushort_t* wb    = ws + 7 * BUF;
    ushort_t* fpW1b = wb;              // G1 Wcat = [fpW1|Wq|Wk|Wv] contiguous
    ushort_t* Wqb   = wb + 102400;
    ushort_t* Wkb   = wb + 204800;
    ushort_t* Wvb   = wb + 307200;
    ushort_t* fpW2b = wb + 409600;
    ushort_t* Wob   = wb + 512000;
    ushort_t* mW1b  = wb + 614400;
    ushort_t* pW1b  = wb + 665600;
    ushort_t* pW2b  = wb + 870400;
    float* probF = (float*)(ws + 7 * BUF + 921600);

    ushort_t* ctxb = xb;               // aliases (see timeline in comments)
    ushort_t* aoB  = qkvb;
    ushort_t* t2b  = qkvb + BUF;
    ushort_t* c1   = qkvb + 2 * BUF;
    ushort_t* t3   = t1b;
    ushort_t* c2   = xb;

    dim3 blk(256);

    // L1: all fp32->bf16 conversions (x + 9 weight matrices), exact block ranges
    ConvPack cp;
    const float* srcs[10] = {x, fpW1, Wq, Wk, Wv, fpW2, Wo, mW1, pW1, pW2};
    ushort_t*    dsts[10] = {xb, fpW1b, Wqb, Wkb, Wvb, fpW2b, Wob, mW1b, pW1b, pW2b};
    const int    nblk[10] = {5120, 100, 100, 100, 100, 100, 100, 50, 200, 50};
    int acc_blk = 0;
    for (int i = 0; i < 10; ++i) {
        cp.d[i].src = srcs[i]; cp.d[i].dst = dsts[i];
        cp.start[i] = acc_blk; acc_blk += nblk[i];
    }
    cp.start[10] = acc_blk;
    conv_all<<<dim3(acc_blk), blk, 0, stream>>>(cp);

    // L2: x -> [fp1 relu | q | k | v]
    k_g1<<<dim3(2560), blk, 0, stream>>>(xb, wb, fpb1, bq, bk, bv, t1b, qkvb);
    // L3: G2 (backbone) || attention
    k_g2_attn<<<dim3(8832), blk, 0, stream>>>(t1b, fpW2b, fpb2, out_bb, bbB, qkvb, ctxb);
    // L4: G3 (Wo proj) || G4 (fp1(bb))
    k_g3_g4<<<dim3(1280), blk, 0, stream>>>(ctxb, Wob, bo, aoB, bbB, fpW1b, fpb1, t2b);
    // L5: G5 (fp2 -> side) || G6 (mW1, N=160)
    k_g5_g6<<<dim3(1280), blk, 0, stream>>>(t2b, fpW2b, fpb2, out_side, sideB, aoB, mW1b, mb1, c1);
    // L6: G7 (pW1, K=640) || rowdot (mW2 -> prob)
    k_g7_rd<<<dim3(4736), blk, 0, stream>>>(bbB, sideB, pW1b, pb1, t3, c1, mW2, mb2, probF);
    // L7: G8 (pW2, N=160) || contact broadcast
    k_g8_ct<<<dim3(17024), blk, 0, stream>>>(t3, pW2b, pb2, c2, probF, out_cm);
    // L8: rowdot (pW3 -> refined)
    k_rd3<<<dim3(4096), blk, 0, stream>>>(c2, pW3, pb3, out_ref);
}